// Round 20
// baseline (1674.081 us; speedup 1.0000x reference)
//
#include <hip/hip_runtime.h>
#include <hip/hip_bf16.h>
#include <math.h>

#define N_NODES   50000
#define N_RELS    100000
#define N_TRIPLES 100000
#define D_IN      512
#define H_DIM     768
#define NUM_LAYERS 3
#define B_IMG     16
#define MP        50176   // 50000 padded to 196*256

typedef __attribute__((ext_vector_type(8))) short short8;
typedef __attribute__((ext_vector_type(4))) float f32x4;

typedef const __attribute__((address_space(1))) unsigned int glb_u32;
typedef __attribute__((address_space(3))) unsigned int lds_u32;

__device__ inline short f2bf16s(float f){
  union { __hip_bfloat16 h; unsigned short u; } cv;
  cv.h = __float2bfloat16(f);          // RNE
  return (short)cv.u;
}
__device__ inline float bf2f(unsigned short u){
  union { unsigned u; float f; } c; c.u = ((unsigned)u)<<16; return c.f;
}
__device__ inline uint2 pack4bf(float4 v){
  uint2 r;
  r.x = ((unsigned)(unsigned short)f2bf16s(v.x)) | (((unsigned)(unsigned short)f2bf16s(v.y))<<16);
  r.y = ((unsigned)(unsigned short)f2bf16s(v.z)) | (((unsigned)(unsigned short)f2bf16s(v.w))<<16);
  return r;
}
__device__ inline float4 unpack4bf(uint2 p){
  float4 v;
  v.x = bf2f((unsigned short)(p.x & 0xffff)); v.y = bf2f((unsigned short)(p.x >> 16));
  v.z = bf2f((unsigned short)(p.y & 0xffff)); v.w = bf2f((unsigned short)(p.y >> 16));
  return v;
}

// ---------- index-dtype detection (int32 vs int64) ----------
__global__ void detect_idx64_kernel(const unsigned* __restrict__ tr, int* __restrict__ flag){
  if (threadIdx.x == 0 && blockIdx.x == 0){
    unsigned o = 0;
    for (int k = 0; k < 256; k++) o |= tr[2*k + 1];
    flag[0] = (o == 0) ? 1 : 0;
  }
}

__device__ inline void load_triple(const void* tp, int t, int is64, int& s, int& r, int& o){
  if (is64){
    const long long* p = (const long long*)tp;
    s = (int)p[3*t]; r = (int)p[3*t+1]; o = (int)p[3*t+2];
  } else {
    const int* p = (const int*)tp;
    s = p[3*t]; r = p[3*t+1]; o = p[3*t+2];
  }
  s = (s < 0) ? 0 : (s >= N_NODES ? N_NODES-1 : s);
  o = (o < 0) ? 0 : (o >= N_NODES ? N_NODES-1 : o);
  r = (r < 0) ? 0 : (r >= N_RELS  ? N_RELS-1  : r);
}

__device__ inline int idx_at(const void* p, int i, int is64){
  return is64 ? (int)((const long long*)p)[i] : ((const int*)p)[i];
}

// ---------- CSR build ----------
__global__ __launch_bounds__(256)
void hist_kernel(const void* __restrict__ tr, const int* __restrict__ flag,
                 int* __restrict__ deg){
  int t = blockIdx.x*256 + threadIdx.x;
  if (t >= N_TRIPLES) return;
  int s, r, o;
  load_triple(tr, t, flag[0], s, r, o);
  atomicAdd(&deg[o], 1);
  atomicAdd(&deg[s], 1);
}

__global__ __launch_bounds__(1024)
void scan_kernel(const int* __restrict__ deg, int* __restrict__ offs,
                 int* __restrict__ cursor, float* __restrict__ cnt){
  __shared__ int partial[1024];
  int tid = threadIdx.x;
  const int per = (N_NODES + 1023)/1024;           // 49
  int start = tid*per, end = start+per; if (end > N_NODES) end = N_NODES;
  if (start > N_NODES) start = N_NODES;
  int s = 0;
  for (int i=start; i<end; i++) s += deg[i];
  partial[tid] = s;
  __syncthreads();
  for (int off=1; off<1024; off<<=1){
    int v = (tid >= off) ? partial[tid-off] : 0;
    __syncthreads();
    partial[tid] += v;
    __syncthreads();
  }
  int run = (tid > 0) ? partial[tid-1] : 0;
  for (int i=start; i<end; i++){
    offs[i] = run; cursor[i] = run; cnt[i] = (float)deg[i];
    run += deg[i];
  }
  if (tid == 1023) offs[N_NODES] = run;
}

__global__ __launch_bounds__(256)
void fill_kernel(const void* __restrict__ tr, const int* __restrict__ flag,
                 int* __restrict__ cursor, int* __restrict__ col_node,
                 int* __restrict__ col_rel){
  int t = blockIdx.x*256 + threadIdx.x;
  if (t >= N_TRIPLES) return;
  int s, r, o;
  load_triple(tr, t, flag[0], s, r, o);
  int p1 = atomicAdd(&cursor[o], 1); col_node[p1] = s; col_rel[p1] = r;
  int p2 = atomicAdd(&cursor[s], 1); col_node[p2] = o; col_rel[p2] = r;
}

// ---------- gathers (CSR, no atomics) ----------
__global__ __launch_bounds__(256)
void gather_rel_bf_kernel(const int* __restrict__ offs, const int* __restrict__ col_rel,
                          const unsigned short* __restrict__ relf_bf,
                          unsigned short* __restrict__ rfa_bf){
  int v = blockIdx.x*4 + (threadIdx.x >> 6);
  int lane = threadIdx.x & 63;
  float4 a0 = {0,0,0,0}, a1 = {0,0,0,0};
  int lo = offs[v], hi = offs[v+1];
  for (int e=lo; e<hi; e++){
    int r = col_rel[e];
    const uint2* rp = (const uint2*)(relf_bf + (size_t)r*D_IN);
    float4 x0 = unpack4bf(rp[lane]);
    float4 x1 = unpack4bf(rp[lane+64]);
    a0.x+=x0.x; a0.y+=x0.y; a0.z+=x0.z; a0.w+=x0.w;
    a1.x+=x1.x; a1.y+=x1.y; a1.z+=x1.z; a1.w+=x1.w;
  }
  uint2* out = (uint2*)(rfa_bf + (size_t)v*D_IN);
  out[lane]    = pack4bf(a0);
  out[lane+64] = pack4bf(a1);
}

// fallback-path rel gather: fp32 source
__global__ __launch_bounds__(256)
void gather_rel_kernel(const int* __restrict__ offs, const int* __restrict__ col_rel,
                       const float* __restrict__ relf, unsigned short* __restrict__ rfa_bf){
  int v = blockIdx.x*4 + (threadIdx.x >> 6);
  int lane = threadIdx.x & 63;
  float4 a0 = {0,0,0,0}, a1 = {0,0,0,0};
  int lo = offs[v], hi = offs[v+1];
  for (int e=lo; e<hi; e++){
    int r = col_rel[e];
    const float* rp = relf + (size_t)r*D_IN + lane*4;
    float4 x0 = *(const float4*)rp;
    float4 x1 = *(const float4*)(rp + 256);
    a0.x+=x0.x; a0.y+=x0.y; a0.z+=x0.z; a0.w+=x0.w;
    a1.x+=x1.x; a1.y+=x1.y; a1.z+=x1.z; a1.w+=x1.w;
  }
  uint2* out = (uint2*)(rfa_bf + (size_t)v*D_IN);
  out[lane]    = pack4bf(a0);
  out[lane+64] = pack4bf(a1);
}

// gather: node states in bf16
__global__ __launch_bounds__(256)
void gather_node_bf_kernel(const int* __restrict__ offs, const int* __restrict__ col_node,
                           const unsigned short* __restrict__ seed_bf,
                           const unsigned short* __restrict__ node_bf,
                           unsigned short* __restrict__ agg_bf){
  int v = blockIdx.x*4 + (threadIdx.x >> 6);
  int lane = threadIdx.x & 63;
  const uint2* sp = (const uint2*)(seed_bf + (size_t)v*H_DIM);
  float4 a0 = unpack4bf(sp[lane]);
  float4 a1 = unpack4bf(sp[lane+64]);
  float4 a2 = unpack4bf(sp[lane+128]);
  int lo = offs[v], hi = offs[v+1];
  for (int e=lo; e<hi; e++){
    int u = col_node[e];
    const uint2* np = (const uint2*)(node_bf + (size_t)u*H_DIM);
    float4 x0 = unpack4bf(np[lane]);
    float4 x1 = unpack4bf(np[lane+64]);
    float4 x2 = unpack4bf(np[lane+128]);
    a0.x+=x0.x; a0.y+=x0.y; a0.z+=x0.z; a0.w+=x0.w;
    a1.x+=x1.x; a1.y+=x1.y; a1.z+=x1.z; a1.w+=x1.w;
    a2.x+=x2.x; a2.y+=x2.y; a2.z+=x2.z; a2.w+=x2.w;
  }
  uint2* out = (uint2*)(agg_bf + (size_t)v*H_DIM);
  out[lane]     = pack4bf(a0);
  out[lane+64]  = pack4bf(a1);
  out[lane+128] = pack4bf(a2);
}

// fallback-path gather: node states fp32
__global__ __launch_bounds__(256)
void gather_node_kernel(const int* __restrict__ offs, const int* __restrict__ col_node,
                        const unsigned short* __restrict__ seed_bf,
                        const float* __restrict__ node,
                        unsigned short* __restrict__ agg_bf){
  int v = blockIdx.x*4 + (threadIdx.x >> 6);
  int lane = threadIdx.x & 63;
  const uint2* sp = (const uint2*)(seed_bf + (size_t)v*H_DIM);
  float4 a0 = unpack4bf(sp[lane]);
  float4 a1 = unpack4bf(sp[lane+64]);
  float4 a2 = unpack4bf(sp[lane+128]);
  int lo = offs[v], hi = offs[v+1];
  for (int e=lo; e<hi; e++){
    int u = col_node[e];
    const float* np = node + (size_t)u*H_DIM + lane*4;
    float4 x0 = *(const float4*)np;
    float4 x1 = *(const float4*)(np + 256);
    float4 x2 = *(const float4*)(np + 512);
    a0.x+=x0.x; a0.y+=x0.y; a0.z+=x0.z; a0.w+=x0.w;
    a1.x+=x1.x; a1.y+=x1.y; a1.z+=x1.z; a1.w+=x1.w;
    a2.x+=x2.x; a2.y+=x2.y; a2.z+=x2.z; a2.w+=x2.w;
  }
  uint2* out = (uint2*)(agg_bf + (size_t)v*H_DIM);
  out[lane]     = pack4bf(a0);
  out[lane+64]  = pack4bf(a1);
  out[lane+128] = pack4bf(a2);
}

// ---------- GEMM helpers ----------
__device__ inline short8 load_cvt8(const float* __restrict__ p, bool valid){
  short8 r;
  if (valid){
    float4 v0 = *(const float4*)(p);
    float4 v1 = *(const float4*)(p+4);
    r[0]=f2bf16s(v0.x); r[1]=f2bf16s(v0.y); r[2]=f2bf16s(v0.z); r[3]=f2bf16s(v0.w);
    r[4]=f2bf16s(v1.x); r[5]=f2bf16s(v1.y); r[6]=f2bf16s(v1.z); r[7]=f2bf16s(v1.w);
  } else {
    r = (short8)0;
  }
  return r;
}

// ====================================================================
// LDS-staged GEMM — r15/r17 geometry (tile 256x128, 8 waves, wave 64x64,
// acc[4][4]) + T3 MINIMUM RECIPE (this round's change): double-buffered
// LDS (96KB), STAGE(next) issued at ITERATION START, compute, then ONE
// vmcnt(0)+s_barrier per K-step at iteration END — load latency hides
// under the full compute phase; r8/r10's failures drained the prefetch
// with a mid-iteration barrier (zero/short cover). Race-free: a wave
// passes the end barrier only after its ds_reads of buf[cur] are
// consumed (compiler lgkmcnt before MFMA use), so next iter's STAGE
// into buf[cur^1] (last read before the previous barrier) is safe.
// MODE 0: Cbf = bf16(acc+bias)
// MODE 2: Cbf = bf16(acc + rowscale[m]*bias)
// MODE 1: Cbf = bf16( bf2f(A1[idx]) + silu(acc+bias) )
// ====================================================================
template<int MODE>
__global__ __launch_bounds__(512)
void gemm_lds(const unsigned short* __restrict__ A1,
              const unsigned short* __restrict__ A2,
              const unsigned short* __restrict__ W,
              const float* __restrict__ bias,
              const float* __restrict__ rowscale,
              unsigned short* __restrict__ Cbf,
              int M, int K1, int K2)
{
  __shared__ unsigned short As[2][256*64];   // 64 KB
  __shared__ unsigned short Bs[2][128*64];   // 32 KB
  const int lane = threadIdx.x & 63;
  const int wv   = threadIdx.x >> 6;      // 0..7
  const int llo  = lane & 15, lhi = lane >> 4;
  const int wm   = (wv>>1)*64;            // 0,64,128,192 (rows)
  const int wn   = (wv&1)*64;             // 0,64        (cols)

  // --- T1: bijective XCD chunk swizzle (m204), then bn-inner decompose ---
  const int nwg  = gridDim.x;             // 1176
  const int q8   = nwg >> 3, r8 = nwg & 7;
  const int xcd  = blockIdx.x & 7, base = blockIdx.x >> 3;
  const int virt = (xcd < r8 ? xcd*(q8+1) : r8*(q8+1) + (xcd-r8)*q8) + base;
  const int bm   = (virt / 6) * 256;
  const int bn   = (virt % 6) * 128;
  const int KW   = K1 + K2;

  // staging: lane loads 16B; row within 8-row chunk = lane>>3, source col16 pre-swizzled
  const int srow = lane >> 3;                    // 0..7
  const int scol = ((lane & 7) ^ srow) * 8;      // element offset (inverse-swz source)

  f32x4 acc[4][4];
  #pragma unroll
  for (int i=0;i<4;i++)
    #pragma unroll
    for (int j=0;j<4;j++) acc[i][j] = (f32x4)(0.0f);

  const unsigned short* Wb = W + (size_t)bn*KW;

#define STAGE(BUF, K0) do{ \
    int k0_ = (K0); \
    const unsigned short* Asrc_; int ak0_, astr_; \
    if (k0_ < K1){ Asrc_ = A1 + (size_t)bm*K1; ak0_ = k0_;      astr_ = K1; } \
    else         { Asrc_ = A2 + (size_t)bm*K2; ak0_ = k0_ - K1; astr_ = K2; } \
    unsigned short* asb_ = As[BUF]; \
    unsigned short* bsb_ = Bs[BUF]; \
    _Pragma("unroll") \
    for (int p_=0;p_<4;p_++){ \
      int c_ = wv*4 + p_; \
      int row_ = c_*8 + srow; \
      __builtin_amdgcn_global_load_lds( \
        (glb_u32*)(Asrc_ + (size_t)row_*astr_ + ak0_ + scol), \
        (lds_u32*)(asb_ + c_*512), 16, 0, 0); \
    } \
    _Pragma("unroll") \
    for (int p_=0;p_<2;p_++){ \
      int c_ = wv*2 + p_; \
      int row_ = c_*8 + srow; \
      __builtin_amdgcn_global_load_lds( \
        (glb_u32*)(Wb + (size_t)row_*KW + k0_ + scol), \
        (lds_u32*)(bsb_ + c_*512), 16, 0, 0); \
    } }while(0)

#define COMPUTE(BUF) do{ \
    const unsigned short* asb_ = As[BUF]; \
    const unsigned short* bsb_ = Bs[BUF]; \
    _Pragma("unroll") \
    for (int kk=0; kk<64; kk+=32){ \
      short8 a_[4], b_[4]; \
      _Pragma("unroll") \
      for (int i=0;i<4;i++){ \
        int rowA_ = wm + i*16 + llo; \
        int rowB_ = wn + i*16 + llo; \
        int c16_  = lhi + (kk>>3); \
        a_[i] = *(const short8*)(asb_ + rowA_*64 + ((c16_ ^ (rowA_&7))*8)); \
        b_[i] = *(const short8*)(bsb_ + rowB_*64 + ((c16_ ^ (rowB_&7))*8)); \
      } \
      _Pragma("unroll") \
      for (int i=0;i<4;i++) \
        _Pragma("unroll") \
        for (int j=0;j<4;j++) \
          acc[i][j] = __builtin_amdgcn_mfma_f32_16x16x32_bf16(a_[i], b_[j], acc[i][j], 0,0,0); \
    } }while(0)

  const int NT = KW/64;   // 8 or 24
  STAGE(0, 0);
  asm volatile("s_waitcnt vmcnt(0)\ns_barrier" ::: "memory");
  int cur = 0;
  for (int t = 0; t < NT; ++t){
    if (t+1 < NT) STAGE(cur^1, (t+1)*64);   // issue-early: hides under COMPUTE
    COMPUTE(cur);
    asm volatile("s_waitcnt vmcnt(0)\ns_barrier" ::: "memory");
    cur ^= 1;
  }
#undef STAGE
#undef COMPUTE

  #pragma unroll
  for (int j=0;j<4;j++){
    int col = bn + wn + j*16 + llo;
    float bv = bias ? bias[col] : 0.0f;
    #pragma unroll
    for (int i=0;i<4;i++){
      #pragma unroll
      for (int r=0;r<4;r++){
        int row = bm + wm + i*16 + lhi*4 + r;
        if (row < M){
          size_t idx = (size_t)row*H_DIM + col;
          float v = acc[i][j][r];
          if (MODE==0){
            Cbf[idx] = (unsigned short)f2bf16s(v + bv);
          } else if (MODE==2){
            v += rowscale[row]*bv;
            Cbf[idx] = (unsigned short)f2bf16s(v);
          } else {
            v += bv;
            float s = v / (1.0f + __expf(-v));   // silu
            float nv = bf2f(A1[idx]) + s;        // A1 == cur (read-only this launch)
            Cbf[idx] = (unsigned short)f2bf16s(nv);
          }
        }
      }
    }
  }
}

// ====================================================================
// FALLBACK PATH (round-5 kernels, used if ws_size is too small)
// ====================================================================
template<int MODE, int ABF>
__global__ __launch_bounds__(256)
void gemm_in(const float* __restrict__ Xf, const unsigned short* __restrict__ Xbf,
             const unsigned short* __restrict__ W,
             const float* __restrict__ bias, const float* __restrict__ rowscale,
             float* __restrict__ Cf, unsigned short* __restrict__ Cbf,
             int M, int Ka)
{
  const int lane = threadIdx.x & 63;
  const int wv   = threadIdx.x >> 6;
  const int llo  = lane & 15, lhi = lane >> 4;
  const int bm   = blockIdx.x*128 + (wv>>1)*64;
  const int bn   = blockIdx.y*128 + (wv&1)*64;

  f32x4 acc[4][4];
  #pragma unroll
  for (int i=0;i<4;i++)
    #pragma unroll
    for (int j=0;j<4;j++) acc[i][j] = (f32x4)(0.0f);

  for (int k0=0;k0<Ka;k0+=32){
    short8 a[4], b[4];
    #pragma unroll
    for (int i=0;i<4;i++){
      int row = bm + i*16 + llo;
      if (ABF) a[i] = (row < M) ? *(const short8*)(Xbf + (size_t)row*Ka + k0 + lhi*8) : (short8)0;
      else     a[i] = load_cvt8(Xf + (size_t)row*Ka + k0 + lhi*8, row < M);
      b[i] = *(const short8*)(W + (size_t)(bn + i*16 + llo)*Ka + k0 + lhi*8);
    }
    #pragma unroll
    for (int i=0;i<4;i++)
      #pragma unroll
      for (int j=0;j<4;j++)
        acc[i][j] = __builtin_amdgcn_mfma_f32_16x16x32_bf16(a[i], b[j], acc[i][j], 0,0,0);
  }

  #pragma unroll
  for (int j=0;j<4;j++){
    int col = bn + j*16 + llo;
    float bv = bias ? bias[col] : 0.0f;
    #pragma unroll
    for (int i=0;i<4;i++){
      #pragma unroll
      for (int r=0;r<4;r++){
        int row = bm + i*16 + lhi*4 + r;
        if (row < M){
          size_t idx = (size_t)row*H_DIM + col;
          float v = acc[i][j][r];
          if (MODE==2){
            v += rowscale[row]*bv;
            Cbf[idx] = (unsigned short)f2bf16s(v);
          } else {
            Cf[idx] = v + bv;
          }
        }
      }
    }
  }
}

__global__ __launch_bounds__(512)
void gemm_layer(float* __restrict__ node,
                const unsigned short* __restrict__ agg_bf,
                const unsigned short* __restrict__ W,
                const float* __restrict__ bias,
                int M)
{
  const int lane = threadIdx.x & 63;
  const int wv   = threadIdx.x >> 6;
  const int llo  = lane & 15, lhi = lane >> 4;
  const int bm   = blockIdx.x*64;
  const int bn   = wv*96;

  f32x4 acc[4][6];
  #pragma unroll
  for (int i=0;i<4;i++)
    #pragma unroll
    for (int j=0;j<6;j++) acc[i][j] = (f32x4)(0.0f);

  for (int k0=0;k0<H_DIM;k0+=32){
    short8 a[4], b[6];
    #pragma unroll
    for (int i=0;i<4;i++){
      int row = bm + i*16 + llo;
      a[i] = load_cvt8(node + (size_t)row*H_DIM + k0 + lhi*8, row < M);
    }
    #pragma unroll
    for (int j=0;j<6;j++)
      b[j] = *(const short8*)(W + (size_t)(bn + j*16 + llo)*(2*H_DIM) + k0 + lhi*8);
    #pragma unroll
    for (int i=0;i<4;i++)
      #pragma unroll
      for (int j=0;j<6;j++)
        acc[i][j] = __builtin_amdgcn_mfma_f32_16x16x32_bf16(a[i], b[j], acc[i][j], 0,0,0);
  }
  for (int k0=0;k0<H_DIM;k0+=32){
    short8 a[4], b[6];
    #pragma unroll
    for (int i=0;i<4;i++){
      int row = bm + i*16 + llo;
      a[i] = (row < M) ? *(const short8*)(agg_bf + (size_t)row*H_DIM + k0 + lhi*8) : (short8)0;
    }
    #pragma unroll
    for (int j=0;j<6;j++)
      b[j] = *(const short8*)(W + (size_t)(bn + j*16 + llo)*(2*H_DIM) + H_DIM + k0 + lhi*8);
    #pragma unroll
    for (int i=0;i<4;i++)
      #pragma unroll
      for (int j=0;j<6;j++)
        acc[i][j] = __builtin_amdgcn_mfma_f32_16x16x32_bf16(a[i], b[j], acc[i][j], 0,0,0);
  }

  __syncthreads();

  #pragma unroll
  for (int j=0;j<6;j++){
    int col = bn + j*16 + llo;
    float bv = bias[col];
    #pragma unroll
    for (int i=0;i<4;i++){
      #pragma unroll
      for (int r=0;r<4;r++){
        int row = bm + i*16 + lhi*4 + r;
        if (row < M){
          size_t idx = (size_t)row*H_DIM + col;
          float v = acc[i][j][r] + bv;
          float s = v / (1.0f + __expf(-v));
          node[idx] += s;
        }
      }
    }
  }
}

// ---------- weight cast ----------
__global__ __launch_bounds__(256)
void cast_bf16_kernel(const float* __restrict__ src, unsigned short* __restrict__ dst,
                      long n){
  long i = ((long)blockIdx.x*blockDim.x + threadIdx.x)*8;
  long stride = (long)gridDim.x*blockDim.x*8;
  for (; i < n; i += stride){
    float4 v0 = *(const float4*)(src+i);
    float4 v1 = *(const float4*)(src+i+4);
    short8 o;
    o[0]=f2bf16s(v0.x); o[1]=f2bf16s(v0.y); o[2]=f2bf16s(v0.z); o[3]=f2bf16s(v0.w);
    o[4]=f2bf16s(v1.x); o[5]=f2bf16s(v1.y); o[6]=f2bf16s(v1.z); o[7]=f2bf16s(v1.w);
    *(short8*)(dst+i) = o;
  }
}

// ---------- LayerNorm fp32-in (fallback) ----------
__global__ __launch_bounds__(256)
void ln_kernel(const float* __restrict__ x, const float* __restrict__ g,
               const float* __restrict__ b, float* __restrict__ out){
  int row = blockIdx.x;
  int t = threadIdx.x;
  const float* xr = x + (size_t)row*H_DIM;
  float v0 = xr[t], v1 = xr[t+256], v2 = xr[t+512];
  float s  = v0+v1+v2;
  float ss = v0*v0+v1*v1+v2*v2;
  for (int off=32; off>0; off>>=1){
    s  += __shfl_down(s,  off);
    ss += __shfl_down(ss, off);
  }
  __shared__ float rs_[4], rss_[4];
  __shared__ float mu_s, rstd_s;
  int lane = t & 63, wv = t >> 6;
  if (lane==0){ rs_[wv]=s; rss_[wv]=ss; }
  __syncthreads();
  if (t==0){
    float S  = rs_[0]+rs_[1]+rs_[2]+rs_[3];
    float SS = rss_[0]+rss_[1]+rss_[2]+rss_[3];
    float mu = S * (1.0f/768.0f);
    float var = SS * (1.0f/768.0f) - mu*mu;
    mu_s = mu; rstd_s = rsqrtf(var + 1e-5f);
  }
  __syncthreads();
  float mu = mu_s, rstd = rstd_s;
  float* orow = out + (size_t)row*H_DIM;
  orow[t]     = (v0-mu)*rstd*g[t]     + b[t];
  orow[t+256] = (v1-mu)*rstd*g[t+256] + b[t+256];
  orow[t+512] = (v2-mu)*rstd*g[t+512] + b[t+512];
}

// ---------- LayerNorm bf16-in, fp32-out (new path) ----------
__global__ __launch_bounds__(256)
void ln_bf_kernel(const unsigned short* __restrict__ xbf, const float* __restrict__ g,
                  const float* __restrict__ b, float* __restrict__ out){
  int row = blockIdx.x;
  int t = threadIdx.x;
  const unsigned short* xr = xbf + (size_t)row*H_DIM;
  float v0 = bf2f(xr[t]), v1 = bf2f(xr[t+256]), v2 = bf2f(xr[t+512]);
  float s  = v0+v1+v2;
  float ss = v0*v0+v1*v1+v2*v2;
  for (int off=32; off>0; off>>=1){
    s  += __shfl_down(s,  off);
    ss += __shfl_down(ss, off);
  }
  __shared__ float rs_[4], rss_[4];
  __shared__ float mu_s, rstd_s;
  int lane = t & 63, wv = t >> 6;
  if (lane==0){ rs_[wv]=s; rss_[wv]=ss; }
  __syncthreads();
  if (t==0){
    float S  = rs_[0]+rs_[1]+rs_[2]+rs_[3];
    float SS = rss_[0]+rss_[1]+rss_[2]+rss_[3];
    float mu = S * (1.0f/768.0f);
    float var = SS * (1.0f/768.0f) - mu*mu;
    mu_s = mu; rstd_s = rsqrtf(var + 1e-5f);
  }
  __syncthreads();
  float mu = mu_s, rstd = rstd_s;
  float* orow = out + (size_t)row*H_DIM;
  orow[t]     = (v0-mu)*rstd*g[t]     + b[t];
  orow[t+256] = (v1-mu)*rstd*g[t+256] + b[t+256];
  orow[t+512] = (v2-mu)*rstd*g[t+512] + b[t+512];
}

// ---------- pooling (two-phase) ----------
__global__ __launch_bounds__(256)
void pool1_kernel(const float* __restrict__ ln, const void* __restrict__ o2i,
                  const int* __restrict__ flag, float* __restrict__ acc){
  const int ROWS = 125;
  int is64 = flag[0];
  int r0 = blockIdx.x*ROWS;
  int t = threadIdx.x;
  float a0=0.f, a1=0.f, a2=0.f;
  int cur = idx_at(o2i, r0, is64);
  cur = (cur < 0) ? 0 : (cur >= B_IMG ? B_IMG-1 : cur);
  for (int r=r0; r<r0+ROWS; r++){
    int img = idx_at(o2i, r, is64);
    img = (img < 0) ? 0 : (img >= B_IMG ? B_IMG-1 : img);
    if (img != cur){
      atomicAdd(&acc[cur*H_DIM + t],       a0);
      atomicAdd(&acc[cur*H_DIM + t + 256], a1);
      atomicAdd(&acc[cur*H_DIM + t + 512], a2);
      a0 = a1 = a2 = 0.f;
      cur = img;
    }
    const float* xr = ln + (size_t)r*H_DIM;
    a0 += xr[t]; a1 += xr[t+256]; a2 += xr[t+512];
  }
  atomicAdd(&acc[cur*H_DIM + t],       a0);
  atomicAdd(&acc[cur*H_DIM + t + 256], a1);
  atomicAdd(&acc[cur*H_DIM + t + 512], a2);
}

__device__ inline int lbound_idx(const void* a, int n, int v, int is64){
  int lo=0, hi=n;
  while (lo<hi){ int m=(lo+hi)>>1; if (idx_at(a,m,is64) < v) lo=m+1; else hi=m; }
  return lo;
}

__global__ __launch_bounds__(256)
void pool2_kernel(const float* __restrict__ acc, const void* __restrict__ o2i,
                  const int* __restrict__ flag, float* __restrict__ gout){
  int is64 = flag[0];
  int img = blockIdx.x;
  int t = threadIdx.x;
  int lo = lbound_idx(o2i, N_NODES, img,   is64);
  int hi = lbound_idx(o2i, N_NODES, img+1, is64);
  float c = (float)(hi-lo);
  if (c < 1.0f) c = 1.0f;
  float inv = 1.0f / c;
  gout[(size_t)img*H_DIM + t]       = acc[img*H_DIM + t]       * inv;
  gout[(size_t)img*H_DIM + t + 256] = acc[img*H_DIM + t + 256] * inv;
  gout[(size_t)img*H_DIM + t + 512] = acc[img*H_DIM + t + 512] * inv;
}

extern "C" void kernel_launch(void* const* d_in, const int* in_sizes, int n_in,
                              void* d_out, int out_size, void* d_ws, size_t ws_size,
                              hipStream_t stream){
  const float* node_feats = (const float*)d_in[0];
  const float* rel_feats  = (const float*)d_in[1];
  const void*  triples    = d_in[2];
  const void*  o2i        = d_in[3];
  const float* node_in_w  = (const float*)d_in[4];
  const float* node_in_b  = (const float*)d_in[5];
  const float* rel_in_w   = (const float*)d_in[6];
  const float* rel_in_b   = (const float*)d_in[7];
  const float* proj_w     = (const float*)d_in[8];
  const float* proj_b     = (const float*)d_in[9];
  const float* ln_g       = (const float*)d_in[10];
  const float* ln_b       = (const float*)d_in[11];

  float* out_nodes  = (float*)d_out;
  float* out_global = (float*)d_out + (size_t)N_NODES*H_DIM;

  const int  tri_blocks = (N_TRIPLES + 255)/256;          // 391
  const int  gat_blocks = N_NODES/4;                      // 12500

  // ---- new-path workspace layout ----
  size_t off = 0;
  auto alloc = [&](size_t bytes)->void*{
    void* r = (char*)d_ws + off; off += (bytes + 255) & ~(size_t)255; return r;
  };
  unsigned short* w_node     = (unsigned short*)alloc((size_t)H_DIM*D_IN*2);
  unsigned short* w_rel      = (unsigned short*)alloc((size_t)H_DIM*D_IN*2);
  unsigned short* w_proj     = (unsigned short*)alloc((size_t)NUM_LAYERS*H_DIM*2*H_DIM*2);
  unsigned short* rel_agg_bf = (unsigned short*)alloc((size_t)MP*H_DIM*2);        // 77.1 MB
  unsigned short* relf_bf    = (unsigned short*)alloc((size_t)N_RELS*D_IN*2);     // 102.4 MB
  unsigned short* shr_bf     = (unsigned short*)alloc((size_t)MP*D_IN*2);         // 51.4 MB (nf then rfa)
  unsigned short* node_bf0   = (unsigned short*)alloc((size_t)MP*H_DIM*2);        // 77.1 MB
  unsigned short* node_bf1   = (unsigned short*)alloc((size_t)MP*H_DIM*2);        // 77.1 MB
  unsigned short* agg_bf     = (unsigned short*)alloc((size_t)MP*H_DIM*2);        // 77.1 MB
  float*          cnt        = (float*)alloc((size_t)N_NODES*4);
  int*            deg        = (int*)alloc((size_t)N_NODES*4);
  int*            offs       = (int*)alloc((size_t)(N_NODES+1)*4);
  int*            cursor     = (int*)alloc((size_t)N_NODES*4);
  int*            col_node   = (int*)alloc((size_t)2*N_TRIPLES*4);
  int*            col_rel    = (int*)alloc((size_t)2*N_TRIPLES*4);
  int*            flag       = (int*)alloc(256);
  float*          pool_acc   = (float*)alloc((size_t)B_IMG*H_DIM*4);
  size_t need_full = off;

  // ---- shared prologue: dtype detect + CSR + weight casts ----
  detect_idx64_kernel<<<1,64,0,stream>>>((const unsigned*)triples, flag);
  hipMemsetAsync(deg, 0, (size_t)N_NODES*4, stream);
  hist_kernel<<<tri_blocks,256,0,stream>>>(triples, flag, deg);
  scan_kernel<<<1,1024,0,stream>>>(deg, offs, cursor, cnt);
  fill_kernel<<<tri_blocks,256,0,stream>>>(triples, flag, cursor, col_node, col_rel);
  cast_bf16_kernel<<<512,256,0,stream>>>(node_in_w, w_node, (long)H_DIM*D_IN);
  cast_bf16_kernel<<<512,256,0,stream>>>(rel_in_w,  w_rel,  (long)H_DIM*D_IN);
  cast_bf16_kernel<<<2048,256,0,stream>>>(proj_w, w_proj, (long)NUM_LAYERS*H_DIM*2*H_DIM);

  if (ws_size >= need_full){
    // ========= NEW PATH: T3-minimum dbuf GEMMs (r17 pipeline otherwise) =========
    const int gg = (MP/256) * (H_DIM/128);   // 196*6 = 1176, 1-D (bn-inner remap)

    // node input GEMM: node_bf0 = bf16(node_feats @ Wn^T + bn)
    cast_bf16_kernel<<<2048,256,0,stream>>>(node_feats, shr_bf, (long)N_NODES*D_IN);
    gemm_lds<0><<<gg,512,0,stream>>>(shr_bf, nullptr, w_node, node_in_b, nullptr,
                                     node_bf0, N_NODES, D_IN, 0);

    // rel path: pre-cast rel_feats to bf16 (L3-resident), gather, GEMM
    cast_bf16_kernel<<<2048,256,0,stream>>>(rel_feats, relf_bf, (long)N_RELS*D_IN);
    gather_rel_bf_kernel<<<gat_blocks,256,0,stream>>>(offs, col_rel, relf_bf, shr_bf);
    gemm_lds<2><<<gg,512,0,stream>>>(shr_bf, nullptr, w_rel, rel_in_b, cnt,
                                     rel_agg_bf, N_NODES, D_IN, 0);

    unsigned short* cur = node_bf0;
    unsigned short* nxt = node_bf1;
    for (int l=0; l<NUM_LAYERS; ++l){
      gather_node_bf_kernel<<<gat_blocks,256,0,stream>>>(offs, col_node, rel_agg_bf,
                                                         cur, agg_bf);
      gemm_lds<1><<<gg,512,0,stream>>>(cur, agg_bf,
                                       w_proj + (size_t)l*H_DIM*2*H_DIM,
                                       proj_b + (size_t)l*H_DIM, nullptr,
                                       nxt, N_NODES, H_DIM, H_DIM);
      unsigned short* t = cur; cur = nxt; nxt = t;
    }

    // epilogue: LN (bf16 in, fp32 out) + two-phase pooling
    ln_bf_kernel<<<N_NODES,256,0,stream>>>(cur, ln_g, ln_b, out_nodes);
    hipMemsetAsync(pool_acc, 0, (size_t)B_IMG*H_DIM*4, stream);
    pool1_kernel<<<400,256,0,stream>>>(out_nodes, o2i, flag, pool_acc);
    pool2_kernel<<<B_IMG,256,0,stream>>>(pool_acc, o2i, flag, out_global);
  } else {
    // ================= FALLBACK (round-5 structure, ~216 MB) =================
    size_t off2 = 0;
    auto alloc2 = [&](size_t bytes)->void*{
      void* r = (char*)d_ws + off2; off2 += (bytes + 255) & ~(size_t)255; return r;
    };
    unsigned short* w_node2  = (unsigned short*)alloc2((size_t)H_DIM*D_IN*2);
    unsigned short* w_rel2   = (unsigned short*)alloc2((size_t)H_DIM*D_IN*2);
    unsigned short* w_proj2  = (unsigned short*)alloc2((size_t)NUM_LAYERS*H_DIM*2*H_DIM*2);
    unsigned short* relagg2  = (unsigned short*)alloc2((size_t)N_NODES*H_DIM*2);
    unsigned short* rfa2     = (unsigned short*)alloc2((size_t)N_NODES*D_IN*2);
    unsigned short* agg2     = (unsigned short*)alloc2((size_t)N_NODES*H_DIM*2);
    float* cnt2   = (float*)alloc2((size_t)N_NODES*4);
    int*   deg2   = (int*)alloc2((size_t)N_NODES*4);
    int*   offs2  = (int*)alloc2((size_t)(N_NODES+1)*4);
    int*   cur2   = (int*)alloc2((size_t)N_NODES*4);
    int*   coln2  = (int*)alloc2((size_t)2*N_TRIPLES*4);
    int*   colr2  = (int*)alloc2((size_t)2*N_TRIPLES*4);
    int*   flag2  = (int*)alloc2(256);
    float* pacc2  = (float*)alloc2((size_t)B_IMG*H_DIM*4);
    if (ws_size < off2) return;

    detect_idx64_kernel<<<1,64,0,stream>>>((const unsigned*)triples, flag2);
    hipMemsetAsync(deg2, 0, (size_t)N_NODES*4, stream);
    hist_kernel<<<tri_blocks,256,0,stream>>>(triples, flag2, deg2);
    scan_kernel<<<1,1024,0,stream>>>(deg2, offs2, cur2, cnt2);
    fill_kernel<<<tri_blocks,256,0,stream>>>(triples, flag2, cur2, coln2, colr2);
    cast_bf16_kernel<<<512,256,0,stream>>>(node_in_w, w_node2, (long)H_DIM*D_IN);
    cast_bf16_kernel<<<512,256,0,stream>>>(rel_in_w,  w_rel2,  (long)H_DIM*D_IN);
    cast_bf16_kernel<<<2048,256,0,stream>>>(proj_w, w_proj2, (long)NUM_LAYERS*H_DIM*2*H_DIM);

    const dim3 gemm_grid((N_NODES + 127)/128, H_DIM/128);
    gemm_in<0,0><<<gemm_grid,256,0,stream>>>(node_feats, nullptr, w_node2, node_in_b, nullptr,
                                             out_nodes, nullptr, N_NODES, D_IN);
    gather_rel_kernel<<<gat_blocks,256,0,stream>>>(offs2, colr2, rel_feats, rfa2);
    gemm_in<2,1><<<gemm_grid,256,0,stream>>>(nullptr, rfa2, w_rel2, rel_in_b, cnt2,
                                             nullptr, relagg2, N_NODES, D_IN);
    for (int l=0; l<NUM_LAYERS; ++l){
      gather_node_kernel<<<gat_blocks,256,0,stream>>>(offs2, coln2, relagg2,
                                                      out_nodes, agg2);
      gemm_layer<<<(N_NODES+63)/64,512,0,stream>>>(out_nodes, agg2,
                                                   w_proj2 + (size_t)l*H_DIM*2*H_DIM,
                                                   proj_b + (size_t)l*H_DIM, N_NODES);
    }

    ln_kernel<<<N_NODES,256,0,stream>>>(out_nodes, ln_g, ln_b, out_nodes);
    hipMemsetAsync(pacc2, 0, (size_t)B_IMG*H_DIM*4, stream);
    pool1_kernel<<<400,256,0,stream>>>(out_nodes, o2i, flag2, pacc2);
    pool2_kernel<<<B_IMG,256,0,stream>>>(pacc2, o2i, flag2, out_global);
  }
}

// Round 21
// 1453.066 us; speedup vs baseline: 1.1521x; 1.1521x over previous
//
#include <hip/hip_runtime.h>
#include <hip/hip_bf16.h>
#include <math.h>

#define N_NODES   50000
#define N_RELS    100000
#define N_TRIPLES 100000
#define D_IN      512
#define H_DIM     768
#define NUM_LAYERS 3
#define B_IMG     16
#define MP        50176   // 50000 padded to 196*256

typedef __attribute__((ext_vector_type(8))) short short8;
typedef __attribute__((ext_vector_type(4))) float f32x4;

typedef const __attribute__((address_space(1))) unsigned int glb_u32;
typedef __attribute__((address_space(3))) unsigned int lds_u32;

__device__ inline short f2bf16s(float f){
  union { __hip_bfloat16 h; unsigned short u; } cv;
  cv.h = __float2bfloat16(f);          // RNE
  return (short)cv.u;
}
__device__ inline float bf2f(unsigned short u){
  union { unsigned u; float f; } c; c.u = ((unsigned)u)<<16; return c.f;
}
__device__ inline uint2 pack4bf(float4 v){
  uint2 r;
  r.x = ((unsigned)(unsigned short)f2bf16s(v.x)) | (((unsigned)(unsigned short)f2bf16s(v.y))<<16);
  r.y = ((unsigned)(unsigned short)f2bf16s(v.z)) | (((unsigned)(unsigned short)f2bf16s(v.w))<<16);
  return r;
}
__device__ inline float4 unpack4bf(uint2 p){
  float4 v;
  v.x = bf2f((unsigned short)(p.x & 0xffff)); v.y = bf2f((unsigned short)(p.x >> 16));
  v.z = bf2f((unsigned short)(p.y & 0xffff)); v.w = bf2f((unsigned short)(p.y >> 16));
  return v;
}

// ---------- index-dtype detection (int32 vs int64) ----------
__global__ void detect_idx64_kernel(const unsigned* __restrict__ tr, int* __restrict__ flag){
  if (threadIdx.x == 0 && blockIdx.x == 0){
    unsigned o = 0;
    for (int k = 0; k < 256; k++) o |= tr[2*k + 1];
    flag[0] = (o == 0) ? 1 : 0;
  }
}

__device__ inline void load_triple(const void* tp, int t, int is64, int& s, int& r, int& o){
  if (is64){
    const long long* p = (const long long*)tp;
    s = (int)p[3*t]; r = (int)p[3*t+1]; o = (int)p[3*t+2];
  } else {
    const int* p = (const int*)tp;
    s = p[3*t]; r = p[3*t+1]; o = p[3*t+2];
  }
  s = (s < 0) ? 0 : (s >= N_NODES ? N_NODES-1 : s);
  o = (o < 0) ? 0 : (o >= N_NODES ? N_NODES-1 : o);
  r = (r < 0) ? 0 : (r >= N_RELS  ? N_RELS-1  : r);
}

__device__ inline int idx_at(const void* p, int i, int is64){
  return is64 ? (int)((const long long*)p)[i] : ((const int*)p)[i];
}

// ---------- CSR build ----------
__global__ __launch_bounds__(256)
void hist_kernel(const void* __restrict__ tr, const int* __restrict__ flag,
                 int* __restrict__ deg){
  int t = blockIdx.x*256 + threadIdx.x;
  if (t >= N_TRIPLES) return;
  int s, r, o;
  load_triple(tr, t, flag[0], s, r, o);
  atomicAdd(&deg[o], 1);
  atomicAdd(&deg[s], 1);
}

__global__ __launch_bounds__(1024)
void scan_kernel(const int* __restrict__ deg, int* __restrict__ offs,
                 int* __restrict__ cursor, float* __restrict__ cnt){
  __shared__ int partial[1024];
  int tid = threadIdx.x;
  const int per = (N_NODES + 1023)/1024;           // 49
  int start = tid*per, end = start+per; if (end > N_NODES) end = N_NODES;
  if (start > N_NODES) start = N_NODES;
  int s = 0;
  for (int i=start; i<end; i++) s += deg[i];
  partial[tid] = s;
  __syncthreads();
  for (int off=1; off<1024; off<<=1){
    int v = (tid >= off) ? partial[tid-off] : 0;
    __syncthreads();
    partial[tid] += v;
    __syncthreads();
  }
  int run = (tid > 0) ? partial[tid-1] : 0;
  for (int i=start; i<end; i++){
    offs[i] = run; cursor[i] = run; cnt[i] = (float)deg[i];
    run += deg[i];
  }
  if (tid == 1023) offs[N_NODES] = run;
}

__global__ __launch_bounds__(256)
void fill_kernel(const void* __restrict__ tr, const int* __restrict__ flag,
                 int* __restrict__ cursor, int* __restrict__ col_node,
                 int* __restrict__ col_rel){
  int t = blockIdx.x*256 + threadIdx.x;
  if (t >= N_TRIPLES) return;
  int s, r, o;
  load_triple(tr, t, flag[0], s, r, o);
  int p1 = atomicAdd(&cursor[o], 1); col_node[p1] = s; col_rel[p1] = r;
  int p2 = atomicAdd(&cursor[s], 1); col_node[p2] = o; col_rel[p2] = r;
}

// ---------- gathers (CSR, no atomics) ----------
__global__ __launch_bounds__(256)
void gather_rel_bf_kernel(const int* __restrict__ offs, const int* __restrict__ col_rel,
                          const unsigned short* __restrict__ relf_bf,
                          unsigned short* __restrict__ rfa_bf){
  int v = blockIdx.x*4 + (threadIdx.x >> 6);
  int lane = threadIdx.x & 63;
  float4 a0 = {0,0,0,0}, a1 = {0,0,0,0};
  int lo = offs[v], hi = offs[v+1];
  for (int e=lo; e<hi; e++){
    int r = col_rel[e];
    const uint2* rp = (const uint2*)(relf_bf + (size_t)r*D_IN);
    float4 x0 = unpack4bf(rp[lane]);
    float4 x1 = unpack4bf(rp[lane+64]);
    a0.x+=x0.x; a0.y+=x0.y; a0.z+=x0.z; a0.w+=x0.w;
    a1.x+=x1.x; a1.y+=x1.y; a1.z+=x1.z; a1.w+=x1.w;
  }
  uint2* out = (uint2*)(rfa_bf + (size_t)v*D_IN);
  out[lane]    = pack4bf(a0);
  out[lane+64] = pack4bf(a1);
}

// fallback-path rel gather: fp32 source
__global__ __launch_bounds__(256)
void gather_rel_kernel(const int* __restrict__ offs, const int* __restrict__ col_rel,
                       const float* __restrict__ relf, unsigned short* __restrict__ rfa_bf){
  int v = blockIdx.x*4 + (threadIdx.x >> 6);
  int lane = threadIdx.x & 63;
  float4 a0 = {0,0,0,0}, a1 = {0,0,0,0};
  int lo = offs[v], hi = offs[v+1];
  for (int e=lo; e<hi; e++){
    int r = col_rel[e];
    const float* rp = relf + (size_t)r*D_IN + lane*4;
    float4 x0 = *(const float4*)rp;
    float4 x1 = *(const float4*)(rp + 256);
    a0.x+=x0.x; a0.y+=x0.y; a0.z+=x0.z; a0.w+=x0.w;
    a1.x+=x1.x; a1.y+=x1.y; a1.z+=x1.z; a1.w+=x1.w;
  }
  uint2* out = (uint2*)(rfa_bf + (size_t)v*D_IN);
  out[lane]    = pack4bf(a0);
  out[lane+64] = pack4bf(a1);
}

// gather: node states in bf16
__global__ __launch_bounds__(256)
void gather_node_bf_kernel(const int* __restrict__ offs, const int* __restrict__ col_node,
                           const unsigned short* __restrict__ seed_bf,
                           const unsigned short* __restrict__ node_bf,
                           unsigned short* __restrict__ agg_bf){
  int v = blockIdx.x*4 + (threadIdx.x >> 6);
  int lane = threadIdx.x & 63;
  const uint2* sp = (const uint2*)(seed_bf + (size_t)v*H_DIM);
  float4 a0 = unpack4bf(sp[lane]);
  float4 a1 = unpack4bf(sp[lane+64]);
  float4 a2 = unpack4bf(sp[lane+128]);
  int lo = offs[v], hi = offs[v+1];
  for (int e=lo; e<hi; e++){
    int u = col_node[e];
    const uint2* np = (const uint2*)(node_bf + (size_t)u*H_DIM);
    float4 x0 = unpack4bf(np[lane]);
    float4 x1 = unpack4bf(np[lane+64]);
    float4 x2 = unpack4bf(np[lane+128]);
    a0.x+=x0.x; a0.y+=x0.y; a0.z+=x0.z; a0.w+=x0.w;
    a1.x+=x1.x; a1.y+=x1.y; a1.z+=x1.z; a1.w+=x1.w;
    a2.x+=x2.x; a2.y+=x2.y; a2.z+=x2.z; a2.w+=x2.w;
  }
  uint2* out = (uint2*)(agg_bf + (size_t)v*H_DIM);
  out[lane]     = pack4bf(a0);
  out[lane+64]  = pack4bf(a1);
  out[lane+128] = pack4bf(a2);
}

// fallback-path gather: node states fp32
__global__ __launch_bounds__(256)
void gather_node_kernel(const int* __restrict__ offs, const int* __restrict__ col_node,
                        const unsigned short* __restrict__ seed_bf,
                        const float* __restrict__ node,
                        unsigned short* __restrict__ agg_bf){
  int v = blockIdx.x*4 + (threadIdx.x >> 6);
  int lane = threadIdx.x & 63;
  const uint2* sp = (const uint2*)(seed_bf + (size_t)v*H_DIM);
  float4 a0 = unpack4bf(sp[lane]);
  float4 a1 = unpack4bf(sp[lane+64]);
  float4 a2 = unpack4bf(sp[lane+128]);
  int lo = offs[v], hi = offs[v+1];
  for (int e=lo; e<hi; e++){
    int u = col_node[e];
    const float* np = node + (size_t)u*H_DIM + lane*4;
    float4 x0 = *(const float4*)np;
    float4 x1 = *(const float4*)(np + 256);
    float4 x2 = *(const float4*)(np + 512);
    a0.x+=x0.x; a0.y+=x0.y; a0.z+=x0.z; a0.w+=x0.w;
    a1.x+=x1.x; a1.y+=x1.y; a1.z+=x1.z; a1.w+=x1.w;
    a2.x+=x2.x; a2.y+=x2.y; a2.z+=x2.z; a2.w+=x2.w;
  }
  uint2* out = (uint2*)(agg_bf + (size_t)v*H_DIM);
  out[lane]     = pack4bf(a0);
  out[lane+64]  = pack4bf(a1);
  out[lane+128] = pack4bf(a2);
}

// ---------- GEMM helpers ----------
__device__ inline short8 load_cvt8(const float* __restrict__ p, bool valid){
  short8 r;
  if (valid){
    float4 v0 = *(const float4*)(p);
    float4 v1 = *(const float4*)(p+4);
    r[0]=f2bf16s(v0.x); r[1]=f2bf16s(v0.y); r[2]=f2bf16s(v0.z); r[3]=f2bf16s(v0.w);
    r[4]=f2bf16s(v1.x); r[5]=f2bf16s(v1.y); r[6]=f2bf16s(v1.z); r[7]=f2bf16s(v1.w);
  } else {
    r = (short8)0;
  }
  return r;
}

// ====================================================================
// LDS-staged GEMM — r15/r17/r19 config (session optimum, 2x reproduced:
// 225us layer GEMM, 56 VGPR, 35.5% occupancy): tile 256x128, 8 waves
// (512 thr), wave 64x64, acc[4][4], LDS 48KB, single-buffer
// stage->sync->compute->sync, T2 XOR-swizzle, T1 bijective XCD remap.
// BF16-only node state. Occupancy law (r8/r10/r11/r14/r16/r18/r20):
// any variant that adds LDS or VGPR to buy latency-cover loses more
// from resident-wave count than it gains from overlap.
// MODE 0: Cbf = bf16(acc+bias)
// MODE 2: Cbf = bf16(acc + rowscale[m]*bias)
// MODE 1: Cbf = bf16( bf2f(A1[idx]) + silu(acc+bias) )   (A1 == cur,
//         read-only this launch; block touches only its own tile)
// ====================================================================
template<int MODE>
__global__ __launch_bounds__(512)
void gemm_lds(const unsigned short* __restrict__ A1,
              const unsigned short* __restrict__ A2,
              const unsigned short* __restrict__ W,
              const float* __restrict__ bias,
              const float* __restrict__ rowscale,
              unsigned short* __restrict__ Cbf,
              int M, int K1, int K2)
{
  __shared__ unsigned short As[256*64];   // 32 KB
  __shared__ unsigned short Bs[128*64];   // 16 KB
  const int lane = threadIdx.x & 63;
  const int wv   = threadIdx.x >> 6;      // 0..7
  const int llo  = lane & 15, lhi = lane >> 4;
  const int wm   = (wv>>1)*64;            // 0,64,128,192 (rows)
  const int wn   = (wv&1)*64;             // 0,64        (cols)

  // --- T1: bijective XCD chunk swizzle (m204), then bn-inner decompose ---
  const int nwg  = gridDim.x;             // 1176
  const int q8   = nwg >> 3, r8 = nwg & 7;
  const int xcd  = blockIdx.x & 7, base = blockIdx.x >> 3;
  const int virt = (xcd < r8 ? xcd*(q8+1) : r8*(q8+1) + (xcd-r8)*q8) + base;
  const int bm   = (virt / 6) * 256;
  const int bn   = (virt % 6) * 128;
  const int KW   = K1 + K2;

  // staging: lane loads 16B; row within 8-row chunk = lane>>3, source col16 pre-swizzled
  const int srow = lane >> 3;                    // 0..7
  const int scol = ((lane & 7) ^ srow) * 8;      // element offset (inverse-swz source)

  f32x4 acc[4][4];
  #pragma unroll
  for (int i=0;i<4;i++)
    #pragma unroll
    for (int j=0;j<4;j++) acc[i][j] = (f32x4)(0.0f);

  const unsigned short* Wb = W + (size_t)bn*KW;

  for (int k0=0; k0<KW; k0+=64){
    const unsigned short* Asrc; int ak0, astr;
    if (k0 < K1){ Asrc = A1 + (size_t)bm*K1; ak0 = k0;      astr = K1; }
    else        { Asrc = A2 + (size_t)bm*K2; ak0 = k0 - K1; astr = K2; }
    // A: 32 chunks of 8 rows (rows 0..255); wave handles 4 chunks
    #pragma unroll
    for (int p=0;p<4;p++){
      int c = wv*4 + p;
      int row = c*8 + srow;
      __builtin_amdgcn_global_load_lds(
        (glb_u32*)(Asrc + (size_t)row*astr + ak0 + scol),
        (lds_u32*)(As + c*512), 16, 0, 0);
    }
    // B: 16 chunks of 8 rows (rows 0..127 of W panel); wave handles 2 chunks
    #pragma unroll
    for (int p=0;p<2;p++){
      int c = wv*2 + p;
      int row = c*8 + srow;
      __builtin_amdgcn_global_load_lds(
        (glb_u32*)(Wb + (size_t)row*KW + k0 + scol),
        (lds_u32*)(Bs + c*512), 16, 0, 0);
    }
    __syncthreads();
    #pragma unroll
    for (int kk=0; kk<64; kk+=32){
      short8 a[4], b[4];
      #pragma unroll
      for (int i=0;i<4;i++){
        int rowA = wm + i*16 + llo;
        int rowB = wn + i*16 + llo;
        int c16  = lhi + (kk>>3);
        a[i] = *(const short8*)(As + rowA*64 + ((c16 ^ (rowA&7))*8));
        b[i] = *(const short8*)(Bs + rowB*64 + ((c16 ^ (rowB&7))*8));
      }
      #pragma unroll
      for (int i=0;i<4;i++)
        #pragma unroll
        for (int j=0;j<4;j++)
          acc[i][j] = __builtin_amdgcn_mfma_f32_16x16x32_bf16(a[i], b[j], acc[i][j], 0,0,0);
    }
    __syncthreads();
  }

  #pragma unroll
  for (int j=0;j<4;j++){
    int col = bn + wn + j*16 + llo;
    float bv = bias ? bias[col] : 0.0f;
    #pragma unroll
    for (int i=0;i<4;i++){
      #pragma unroll
      for (int r=0;r<4;r++){
        int row = bm + wm + i*16 + lhi*4 + r;
        if (row < M){
          size_t idx = (size_t)row*H_DIM + col;
          float v = acc[i][j][r];
          if (MODE==0){
            Cbf[idx] = (unsigned short)f2bf16s(v + bv);
          } else if (MODE==2){
            v += rowscale[row]*bv;
            Cbf[idx] = (unsigned short)f2bf16s(v);
          } else {
            v += bv;
            float s = v / (1.0f + __expf(-v));   // silu
            float nv = bf2f(A1[idx]) + s;        // A1 == cur (read-only this launch)
            Cbf[idx] = (unsigned short)f2bf16s(nv);
          }
        }
      }
    }
  }
}

// ====================================================================
// FALLBACK PATH (round-5 kernels, used if ws_size is too small)
// ====================================================================
template<int MODE, int ABF>
__global__ __launch_bounds__(256)
void gemm_in(const float* __restrict__ Xf, const unsigned short* __restrict__ Xbf,
             const unsigned short* __restrict__ W,
             const float* __restrict__ bias, const float* __restrict__ rowscale,
             float* __restrict__ Cf, unsigned short* __restrict__ Cbf,
             int M, int Ka)
{
  const int lane = threadIdx.x & 63;
  const int wv   = threadIdx.x >> 6;
  const int llo  = lane & 15, lhi = lane >> 4;
  const int bm   = blockIdx.x*128 + (wv>>1)*64;
  const int bn   = blockIdx.y*128 + (wv&1)*64;

  f32x4 acc[4][4];
  #pragma unroll
  for (int i=0;i<4;i++)
    #pragma unroll
    for (int j=0;j<4;j++) acc[i][j] = (f32x4)(0.0f);

  for (int k0=0;k0<Ka;k0+=32){
    short8 a[4], b[4];
    #pragma unroll
    for (int i=0;i<4;i++){
      int row = bm + i*16 + llo;
      if (ABF) a[i] = (row < M) ? *(const short8*)(Xbf + (size_t)row*Ka + k0 + lhi*8) : (short8)0;
      else     a[i] = load_cvt8(Xf + (size_t)row*Ka + k0 + lhi*8, row < M);
      b[i] = *(const short8*)(W + (size_t)(bn + i*16 + llo)*Ka + k0 + lhi*8);
    }
    #pragma unroll
    for (int i=0;i<4;i++)
      #pragma unroll
      for (int j=0;j<4;j++)
        acc[i][j] = __builtin_amdgcn_mfma_f32_16x16x32_bf16(a[i], b[j], acc[i][j], 0,0,0);
  }

  #pragma unroll
  for (int j=0;j<4;j++){
    int col = bn + j*16 + llo;
    float bv = bias ? bias[col] : 0.0f;
    #pragma unroll
    for (int i=0;i<4;i++){
      #pragma unroll
      for (int r=0;r<4;r++){
        int row = bm + i*16 + lhi*4 + r;
        if (row < M){
          size_t idx = (size_t)row*H_DIM + col;
          float v = acc[i][j][r];
          if (MODE==2){
            v += rowscale[row]*bv;
            Cbf[idx] = (unsigned short)f2bf16s(v);
          } else {
            Cf[idx] = v + bv;
          }
        }
      }
    }
  }
}

__global__ __launch_bounds__(512)
void gemm_layer(float* __restrict__ node,
                const unsigned short* __restrict__ agg_bf,
                const unsigned short* __restrict__ W,
                const float* __restrict__ bias,
                int M)
{
  const int lane = threadIdx.x & 63;
  const int wv   = threadIdx.x >> 6;
  const int llo  = lane & 15, lhi = lane >> 4;
  const int bm   = blockIdx.x*64;
  const int bn   = wv*96;

  f32x4 acc[4][6];
  #pragma unroll
  for (int i=0;i<4;i++)
    #pragma unroll
    for (int j=0;j<6;j++) acc[i][j] = (f32x4)(0.0f);

  for (int k0=0;k0<H_DIM;k0+=32){
    short8 a[4], b[6];
    #pragma unroll
    for (int i=0;i<4;i++){
      int row = bm + i*16 + llo;
      a[i] = load_cvt8(node + (size_t)row*H_DIM + k0 + lhi*8, row < M);
    }
    #pragma unroll
    for (int j=0;j<6;j++)
      b[j] = *(const short8*)(W + (size_t)(bn + j*16 + llo)*(2*H_DIM) + k0 + lhi*8);
    #pragma unroll
    for (int i=0;i<4;i++)
      #pragma unroll
      for (int j=0;j<6;j++)
        acc[i][j] = __builtin_amdgcn_mfma_f32_16x16x32_bf16(a[i], b[j], acc[i][j], 0,0,0);
  }
  for (int k0=0;k0<H_DIM;k0+=32){
    short8 a[4], b[6];
    #pragma unroll
    for (int i=0;i<4;i++){
      int row = bm + i*16 + llo;
      a[i] = (row < M) ? *(const short8*)(agg_bf + (size_t)row*H_DIM + k0 + lhi*8) : (short8)0;
    }
    #pragma unroll
    for (int j=0;j<6;j++)
      b[j] = *(const short8*)(W + (size_t)(bn + j*16 + llo)*(2*H_DIM) + H_DIM + k0 + lhi*8);
    #pragma unroll
    for (int i=0;i<4;i++)
      #pragma unroll
      for (int j=0;j<6;j++)
        acc[i][j] = __builtin_amdgcn_mfma_f32_16x16x32_bf16(a[i], b[j], acc[i][j], 0,0,0);
  }

  __syncthreads();

  #pragma unroll
  for (int j=0;j<6;j++){
    int col = bn + j*16 + llo;
    float bv = bias[col];
    #pragma unroll
    for (int i=0;i<4;i++){
      #pragma unroll
      for (int r=0;r<4;r++){
        int row = bm + i*16 + lhi*4 + r;
        if (row < M){
          size_t idx = (size_t)row*H_DIM + col;
          float v = acc[i][j][r] + bv;
          float s = v / (1.0f + __expf(-v));
          node[idx] += s;
        }
      }
    }
  }
}

// ---------- weight cast ----------
__global__ __launch_bounds__(256)
void cast_bf16_kernel(const float* __restrict__ src, unsigned short* __restrict__ dst,
                      long n){
  long i = ((long)blockIdx.x*blockDim.x + threadIdx.x)*8;
  long stride = (long)gridDim.x*blockDim.x*8;
  for (; i < n; i += stride){
    float4 v0 = *(const float4*)(src+i);
    float4 v1 = *(const float4*)(src+i+4);
    short8 o;
    o[0]=f2bf16s(v0.x); o[1]=f2bf16s(v0.y); o[2]=f2bf16s(v0.z); o[3]=f2bf16s(v0.w);
    o[4]=f2bf16s(v1.x); o[5]=f2bf16s(v1.y); o[6]=f2bf16s(v1.z); o[7]=f2bf16s(v1.w);
    *(short8*)(dst+i) = o;
  }
}

// ---------- LayerNorm fp32-in (fallback) ----------
__global__ __launch_bounds__(256)
void ln_kernel(const float* __restrict__ x, const float* __restrict__ g,
               const float* __restrict__ b, float* __restrict__ out){
  int row = blockIdx.x;
  int t = threadIdx.x;
  const float* xr = x + (size_t)row*H_DIM;
  float v0 = xr[t], v1 = xr[t+256], v2 = xr[t+512];
  float s  = v0+v1+v2;
  float ss = v0*v0+v1*v1+v2*v2;
  for (int off=32; off>0; off>>=1){
    s  += __shfl_down(s,  off);
    ss += __shfl_down(ss, off);
  }
  __shared__ float rs_[4], rss_[4];
  __shared__ float mu_s, rstd_s;
  int lane = t & 63, wv = t >> 6;
  if (lane==0){ rs_[wv]=s; rss_[wv]=ss; }
  __syncthreads();
  if (t==0){
    float S  = rs_[0]+rs_[1]+rs_[2]+rs_[3];
    float SS = rss_[0]+rss_[1]+rss_[2]+rss_[3];
    float mu = S * (1.0f/768.0f);
    float var = SS * (1.0f/768.0f) - mu*mu;
    mu_s = mu; rstd_s = rsqrtf(var + 1e-5f);
  }
  __syncthreads();
  float mu = mu_s, rstd = rstd_s;
  float* orow = out + (size_t)row*H_DIM;
  orow[t]     = (v0-mu)*rstd*g[t]     + b[t];
  orow[t+256] = (v1-mu)*rstd*g[t+256] + b[t+256];
  orow[t+512] = (v2-mu)*rstd*g[t+512] + b[t+512];
}

// ---------- LayerNorm bf16-in, fp32-out (new path) ----------
__global__ __launch_bounds__(256)
void ln_bf_kernel(const unsigned short* __restrict__ xbf, const float* __restrict__ g,
                  const float* __restrict__ b, float* __restrict__ out){
  int row = blockIdx.x;
  int t = threadIdx.x;
  const unsigned short* xr = xbf + (size_t)row*H_DIM;
  float v0 = bf2f(xr[t]), v1 = bf2f(xr[t+256]), v2 = bf2f(xr[t+512]);
  float s  = v0+v1+v2;
  float ss = v0*v0+v1*v1+v2*v2;
  for (int off=32; off>0; off>>=1){
    s  += __shfl_down(s,  off);
    ss += __shfl_down(ss, off);
  }
  __shared__ float rs_[4], rss_[4];
  __shared__ float mu_s, rstd_s;
  int lane = t & 63, wv = t >> 6;
  if (lane==0){ rs_[wv]=s; rss_[wv]=ss; }
  __syncthreads();
  if (t==0){
    float S  = rs_[0]+rs_[1]+rs_[2]+rs_[3];
    float SS = rss_[0]+rss_[1]+rss_[2]+rss_[3];
    float mu = S * (1.0f/768.0f);
    float var = SS * (1.0f/768.0f) - mu*mu;
    mu_s = mu; rstd_s = rsqrtf(var + 1e-5f);
  }
  __syncthreads();
  float mu = mu_s, rstd = rstd_s;
  float* orow = out + (size_t)row*H_DIM;
  orow[t]     = (v0-mu)*rstd*g[t]     + b[t];
  orow[t+256] = (v1-mu)*rstd*g[t+256] + b[t+256];
  orow[t+512] = (v2-mu)*rstd*g[t+512] + b[t+512];
}

// ---------- pooling (two-phase) ----------
__global__ __launch_bounds__(256)
void pool1_kernel(const float* __restrict__ ln, const void* __restrict__ o2i,
                  const int* __restrict__ flag, float* __restrict__ acc){
  const int ROWS = 125;
  int is64 = flag[0];
  int r0 = blockIdx.x*ROWS;
  int t = threadIdx.x;
  float a0=0.f, a1=0.f, a2=0.f;
  int cur = idx_at(o2i, r0, is64);
  cur = (cur < 0) ? 0 : (cur >= B_IMG ? B_IMG-1 : cur);
  for (int r=r0; r<r0+ROWS; r++){
    int img = idx_at(o2i, r, is64);
    img = (img < 0) ? 0 : (img >= B_IMG ? B_IMG-1 : img);
    if (img != cur){
      atomicAdd(&acc[cur*H_DIM + t],       a0);
      atomicAdd(&acc[cur*H_DIM + t + 256], a1);
      atomicAdd(&acc[cur*H_DIM + t + 512], a2);
      a0 = a1 = a2 = 0.f;
      cur = img;
    }
    const float* xr = ln + (size_t)r*H_DIM;
    a0 += xr[t]; a1 += xr[t+256]; a2 += xr[t+512];
  }
  atomicAdd(&acc[cur*H_DIM + t],       a0);
  atomicAdd(&acc[cur*H_DIM + t + 256], a1);
  atomicAdd(&acc[cur*H_DIM + t + 512], a2);
}

__device__ inline int lbound_idx(const void* a, int n, int v, int is64){
  int lo=0, hi=n;
  while (lo<hi){ int m=(lo+hi)>>1; if (idx_at(a,m,is64) < v) lo=m+1; else hi=m; }
  return lo;
}

__global__ __launch_bounds__(256)
void pool2_kernel(const float* __restrict__ acc, const void* __restrict__ o2i,
                  const int* __restrict__ flag, float* __restrict__ gout){
  int is64 = flag[0];
  int img = blockIdx.x;
  int t = threadIdx.x;
  int lo = lbound_idx(o2i, N_NODES, img,   is64);
  int hi = lbound_idx(o2i, N_NODES, img+1, is64);
  float c = (float)(hi-lo);
  if (c < 1.0f) c = 1.0f;
  float inv = 1.0f / c;
  gout[(size_t)img*H_DIM + t]       = acc[img*H_DIM + t]       * inv;
  gout[(size_t)img*H_DIM + t + 256] = acc[img*H_DIM + t + 256] * inv;
  gout[(size_t)img*H_DIM + t + 512] = acc[img*H_DIM + t + 512] * inv;
}

extern "C" void kernel_launch(void* const* d_in, const int* in_sizes, int n_in,
                              void* d_out, int out_size, void* d_ws, size_t ws_size,
                              hipStream_t stream){
  const float* node_feats = (const float*)d_in[0];
  const float* rel_feats  = (const float*)d_in[1];
  const void*  triples    = d_in[2];
  const void*  o2i        = d_in[3];
  const float* node_in_w  = (const float*)d_in[4];
  const float* node_in_b  = (const float*)d_in[5];
  const float* rel_in_w   = (const float*)d_in[6];
  const float* rel_in_b   = (const float*)d_in[7];
  const float* proj_w     = (const float*)d_in[8];
  const float* proj_b     = (const float*)d_in[9];
  const float* ln_g       = (const float*)d_in[10];
  const float* ln_b       = (const float*)d_in[11];

  float* out_nodes  = (float*)d_out;
  float* out_global = (float*)d_out + (size_t)N_NODES*H_DIM;

  const int  tri_blocks = (N_TRIPLES + 255)/256;          // 391
  const int  gat_blocks = N_NODES/4;                      // 12500

  // ---- new-path workspace layout ----
  size_t off = 0;
  auto alloc = [&](size_t bytes)->void*{
    void* r = (char*)d_ws + off; off += (bytes + 255) & ~(size_t)255; return r;
  };
  unsigned short* w_node     = (unsigned short*)alloc((size_t)H_DIM*D_IN*2);
  unsigned short* w_rel      = (unsigned short*)alloc((size_t)H_DIM*D_IN*2);
  unsigned short* w_proj     = (unsigned short*)alloc((size_t)NUM_LAYERS*H_DIM*2*H_DIM*2);
  unsigned short* rel_agg_bf = (unsigned short*)alloc((size_t)MP*H_DIM*2);        // 77.1 MB
  unsigned short* relf_bf    = (unsigned short*)alloc((size_t)N_RELS*D_IN*2);     // 102.4 MB
  unsigned short* shr_bf     = (unsigned short*)alloc((size_t)MP*D_IN*2);         // 51.4 MB (nf then rfa)
  unsigned short* node_bf0   = (unsigned short*)alloc((size_t)MP*H_DIM*2);        // 77.1 MB
  unsigned short* node_bf1   = (unsigned short*)alloc((size_t)MP*H_DIM*2);        // 77.1 MB
  unsigned short* agg_bf     = (unsigned short*)alloc((size_t)MP*H_DIM*2);        // 77.1 MB
  float*          cnt        = (float*)alloc((size_t)N_NODES*4);
  int*            deg        = (int*)alloc((size_t)N_NODES*4);
  int*            offs       = (int*)alloc((size_t)(N_NODES+1)*4);
  int*            cursor     = (int*)alloc((size_t)N_NODES*4);
  int*            col_node   = (int*)alloc((size_t)2*N_TRIPLES*4);
  int*            col_rel    = (int*)alloc((size_t)2*N_TRIPLES*4);
  int*            flag       = (int*)alloc(256);
  float*          pool_acc   = (float*)alloc((size_t)B_IMG*H_DIM*4);
  size_t need_full = off;

  // ---- shared prologue: dtype detect + CSR + weight casts ----
  detect_idx64_kernel<<<1,64,0,stream>>>((const unsigned*)triples, flag);
  hipMemsetAsync(deg, 0, (size_t)N_NODES*4, stream);
  hist_kernel<<<tri_blocks,256,0,stream>>>(triples, flag, deg);
  scan_kernel<<<1,1024,0,stream>>>(deg, offs, cursor, cnt);
  fill_kernel<<<tri_blocks,256,0,stream>>>(triples, flag, cursor, col_node, col_rel);
  cast_bf16_kernel<<<512,256,0,stream>>>(node_in_w, w_node, (long)H_DIM*D_IN);
  cast_bf16_kernel<<<512,256,0,stream>>>(rel_in_w,  w_rel,  (long)H_DIM*D_IN);
  cast_bf16_kernel<<<2048,256,0,stream>>>(proj_w, w_proj, (long)NUM_LAYERS*H_DIM*2*H_DIM);

  if (ws_size >= need_full){
    // ========= NEW PATH: r17/r19 best config (session optimum) =========
    const int gg = (MP/256) * (H_DIM/128);   // 196*6 = 1176, 1-D (bn-inner remap)

    // node input GEMM: node_bf0 = bf16(node_feats @ Wn^T + bn)
    cast_bf16_kernel<<<2048,256,0,stream>>>(node_feats, shr_bf, (long)N_NODES*D_IN);
    gemm_lds<0><<<gg,512,0,stream>>>(shr_bf, nullptr, w_node, node_in_b, nullptr,
                                     node_bf0, N_NODES, D_IN, 0);

    // rel path: pre-cast rel_feats to bf16 (L3-resident), gather, GEMM
    cast_bf16_kernel<<<2048,256,0,stream>>>(rel_feats, relf_bf, (long)N_RELS*D_IN);
    gather_rel_bf_kernel<<<gat_blocks,256,0,stream>>>(offs, col_rel, relf_bf, shr_bf);
    gemm_lds<2><<<gg,512,0,stream>>>(shr_bf, nullptr, w_rel, rel_in_b, cnt,
                                     rel_agg_bf, N_NODES, D_IN, 0);

    unsigned short* cur = node_bf0;
    unsigned short* nxt = node_bf1;
    for (int l=0; l<NUM_LAYERS; ++l){
      gather_node_bf_kernel<<<gat_blocks,256,0,stream>>>(offs, col_node, rel_agg_bf,
                                                         cur, agg_bf);
      gemm_lds<1><<<gg,512,0,stream>>>(cur, agg_bf,
                                       w_proj + (size_t)l*H_DIM*2*H_DIM,
                                       proj_b + (size_t)l*H_DIM, nullptr,
                                       nxt, N_NODES, H_DIM, H_DIM);
      unsigned short* t = cur; cur = nxt; nxt = t;
    }

    // epilogue: LN (bf16 in, fp32 out) + two-phase pooling
    ln_bf_kernel<<<N_NODES,256,0,stream>>>(cur, ln_g, ln_b, out_nodes);
    hipMemsetAsync(pool_acc, 0, (size_t)B_IMG*H_DIM*4, stream);
    pool1_kernel<<<400,256,0,stream>>>(out_nodes, o2i, flag, pool_acc);
    pool2_kernel<<<B_IMG,256,0,stream>>>(pool_acc, o2i, flag, out_global);
  } else {
    // ================= FALLBACK (round-5 structure, ~216 MB) =================
    size_t off2 = 0;
    auto alloc2 = [&](size_t bytes)->void*{
      void* r = (char*)d_ws + off2; off2 += (bytes + 255) & ~(size_t)255; return r;
    };
    unsigned short* w_node2  = (unsigned short*)alloc2((size_t)H_DIM*D_IN*2);
    unsigned short* w_rel2   = (unsigned short*)alloc2((size_t)H_DIM*D_IN*2);
    unsigned short* w_proj2  = (unsigned short*)alloc2((size_t)NUM_LAYERS*H_DIM*2*H_DIM*2);
    unsigned short* relagg2  = (unsigned short*)alloc2((size_t)N_NODES*H_DIM*2);
    unsigned short* rfa2     = (unsigned short*)alloc2((size_t)N_NODES*D_IN*2);
    unsigned short* agg2     = (unsigned short*)alloc2((size_t)N_NODES*H_DIM*2);
    float* cnt2   = (float*)alloc2((size_t)N_NODES*4);
    int*   deg2   = (int*)alloc2((size_t)N_NODES*4);
    int*   offs2  = (int*)alloc2((size_t)(N_NODES+1)*4);
    int*   cur2   = (int*)alloc2((size_t)N_NODES*4);
    int*   coln2  = (int*)alloc2((size_t)2*N_TRIPLES*4);
    int*   colr2  = (int*)alloc2((size_t)2*N_TRIPLES*4);
    int*   flag2  = (int*)alloc2(256);
    float* pacc2  = (float*)alloc2((size_t)B_IMG*H_DIM*4);
    if (ws_size < off2) return;

    detect_idx64_kernel<<<1,64,0,stream>>>((const unsigned*)triples, flag2);
    hipMemsetAsync(deg2, 0, (size_t)N_NODES*4, stream);
    hist_kernel<<<tri_blocks,256,0,stream>>>(triples, flag2, deg2);
    scan_kernel<<<1,1024,0,stream>>>(deg2, offs2, cur2, cnt2);
    fill_kernel<<<tri_blocks,256,0,stream>>>(triples, flag2, cur2, coln2, colr2);
    cast_bf16_kernel<<<512,256,0,stream>>>(node_in_w, w_node2, (long)H_DIM*D_IN);
    cast_bf16_kernel<<<512,256,0,stream>>>(rel_in_w,  w_rel2,  (long)H_DIM*D_IN);
    cast_bf16_kernel<<<2048,256,0,stream>>>(proj_w, w_proj2, (long)NUM_LAYERS*H_DIM*2*H_DIM);

    const dim3 gemm_grid((N_NODES + 127)/128, H_DIM/128);
    gemm_in<0,0><<<gemm_grid,256,0,stream>>>(node_feats, nullptr, w_node2, node_in_b, nullptr,
                                             out_nodes, nullptr, N_NODES, D_IN);
    gather_rel_kernel<<<gat_blocks,256,0,stream>>>(offs2, colr2, rel_feats, rfa2);
    gemm_in<2,1><<<gemm_grid,256,0,stream>>>(nullptr, rfa2, w_rel2, rel_in_b, cnt2,
                                             nullptr, relagg2, N_NODES, D_IN);
    for (int l=0; l<NUM_LAYERS; ++l){
      gather_node_kernel<<<gat_blocks,256,0,stream>>>(offs2, coln2, relagg2,
                                                      out_nodes, agg2);
      gemm_layer<<<(N_NODES+63)/64,512,0,stream>>>(out_nodes, agg2,
                                                   w_proj2 + (size_t)l*H_DIM*2*H_DIM,
                                                   proj_b + (size_t)l*H_DIM, N_NODES);
    }

    ln_kernel<<<N_NODES,256,0,stream>>>(out_nodes, ln_g, ln_b, out_nodes);
    hipMemsetAsync(pacc2, 0, (size_t)B_IMG*H_DIM*4, stream);
    pool1_kernel<<<400,256,0,stream>>>(out_nodes, o2i, flag2, pacc2);
    pool2_kernel<<<B_IMG,256,0,stream>>>(pacc2, o2i, flag2, out_global);
  }
}